// Round 1
// baseline (107.686 us; speedup 1.0000x reference)
//
#include <hip/hip_runtime.h>
#include <math.h>

#define FF 4096
#define NPAIR 2048
#define BB 32
#define CC 512
#define NEWF 3073   // int(1 + 4096*0.75)

// ---------------------------------------------------------------------------
// Kernel A: pred[b][f2][{0,1}] = dot(x[2*f2,b,:], W[o,:]) + bias[o]  (fp64)
// One wave per (f2,b) row; 4 waves/block.
// ---------------------------------------------------------------------------
__global__ __launch_bounds__(256) void pred_kernel(
    const float* __restrict__ x, const float* __restrict__ W,
    const float* __restrict__ bias, double* __restrict__ pred) {
  int wave = threadIdx.x >> 6;
  int lane = threadIdx.x & 63;
  int row  = blockIdx.x * 4 + wave;        // row in [0, NPAIR*BB)
  int f2 = row >> 5;                        // / BB
  int b  = row & 31;
  const float* xr = x + ((size_t)(2 * f2) * BB + b) * CC;

  double s0 = 0.0, s1 = 0.0;
#pragma unroll
  for (int k = 0; k < 2; ++k) {
    int c = lane * 4 + k * 256;
    float4 xv = *(const float4*)(xr + c);
    float4 w0 = *(const float4*)(W + c);
    float4 w1 = *(const float4*)(W + CC + c);
    s0 += (double)xv.x * (double)w0.x + (double)xv.y * (double)w0.y +
          (double)xv.z * (double)w0.z + (double)xv.w * (double)w0.w;
    s1 += (double)xv.x * (double)w1.x + (double)xv.y * (double)w1.y +
          (double)xv.z * (double)w1.z + (double)xv.w * (double)w1.w;
  }
#pragma unroll
  for (int off = 32; off; off >>= 1) {
    s0 += __shfl_down(s0, off, 64);
    s1 += __shfl_down(s1, off, 64);
  }
  if (lane == 0) {
    size_t o = ((size_t)b * NPAIR + f2) * 2;
    pred[o + 0] = s0 + (double)bias[0];
    pred[o + 1] = s1 + (double)bias[1];
  }
}

// ---------------------------------------------------------------------------
// Kernel C: per-b std, keep decisions, cumsum scan, per-slot contributor
// records, is_sep counts, new_lengths, seq_losses. One block per b.
// rec bit layout: bit0 valid | bit1 two-contributors | bit2 scale-half | f<<3
// ---------------------------------------------------------------------------
__global__ __launch_bounds__(256) void scan_kernel(
    const double* __restrict__ pred, const float* __restrict__ rand_u,
    const int* __restrict__ lengths, int* __restrict__ rec,
    int* __restrict__ sep, float* __restrict__ out_tail) {
  int b = blockIdx.x;
  int t = threadIdx.x;

  __shared__ double sdbl[256];
  __shared__ int    sint[256];
  __shared__ int    sep_lds[NEWF];
  __shared__ double s_inv;

  int len = lengths[b];

  // load 8 pairs of pred, accumulate sum of centered^2 (fp64)
  double p0[8], p1[8];
  double sumsq = 0.0;
  const double* pb = pred + (size_t)b * NPAIR * 2;
#pragma unroll
  for (int i = 0; i < 8; ++i) {
    int pr = t * 8 + i;
    p0[i] = pb[pr * 2 + 0];
    p1[i] = pb[pr * 2 + 1];
    double c = (p0[i] - p1[i]) * 0.5;
    sumsq += c * c;
  }
  sdbl[t] = sumsq;
  __syncthreads();
  for (int off = 128; off; off >>= 1) {
    if (t < off) sdbl[t] += sdbl[t + off];
    __syncthreads();
  }
  if (t == 0) {
    double sd = sqrt(sdbl[0] / (double)NPAIR + 1e-20);
    s_inv = -3.0 / sd;   // SCORE_STDDEV = 3
  }

  // zero-init rec column for this b, and LDS sep counts
  for (int s = t; s < NEWF; s += 256) rec[s * BB + b] = 0;
  for (int s = t; s < NEWF; s += 256) sep_lds[s] = 0;
  __syncthreads();

  // decisions for 8 pairs (16 frames)
  int keptm = 0, onem_e = 0, onem_o = 0;
  double seq = 0.0;
  int cnt = 0;
#pragma unroll
  for (int i = 0; i < 8; ++i) {
    int pr = t * 8 + i;
    double z = (p0[i] - p1[i]) * s_inv;               // = 2*score0
    double prob = 1.0 / (1.0 + exp(-z));              // softmax(..)[0]
    bool kept = prob > (double)rand_u[(size_t)pr * BB + b];
    seq += kept ? p0[i] : p1[i];
    bool oe = ((2 * pr) < len) && kept;
    bool oo = (2 * pr + 1) < len;
    if (kept) keptm |= (1 << i);
    if (oe) onem_e |= (1 << i);
    if (oo) onem_o |= (1 << i);
    cnt += (int)oe + (int)oo;
  }

  // block-wide inclusive scan (Hillis-Steele) of per-thread counts
  sint[t] = cnt;
  __syncthreads();
  for (int off = 1; off < 256; off <<= 1) {
    int v = (t >= off) ? sint[t - off] : 0;
    __syncthreads();
    sint[t] += v;
    __syncthreads();
  }
  int base  = sint[t] - cnt;
  int total = sint[255];

  // walk frames in order: write slot records + sep counts
  int excl = base;
#pragma unroll
  for (int i = 0; i < 8; ++i) {
    int pr = t * 8 + i;
    int fe = 2 * pr, fo = fe + 1;
    bool kept = (keptm >> i) & 1;
    bool oe = (onem_e >> i) & 1;
    bool oo = (onem_o >> i) & 1;
    int excl_e = excl; excl += (int)oe;
    int excl_o = excl; excl += (int)oo;

    // even frame is a (single) contributor when kept & in-length
    if (oe && excl_e < NEWF) {
      int half = oo ? 0 : 1;                 // pair_mean 1.0 or 0.5
      rec[excl_e * BB + b] = 1 | (half << 2) | (fe << 3);
    }
    // odd in-length frame: single (pair kept) or two-contributor (pair dropped)
    if (oo && excl_o < NEWF) {
      int two  = kept ? 0 : 1;
      int half = kept ? 0 : 1;
      rec[excl_o * BB + b] = 1 | (two << 1) | (half << 2) | (fo << 3);
    }
    // boundary: odd past length but even partner kept -> scale 0.5 contributor
    if (!oo && oe && excl_o < NEWF) {
      rec[excl_o * BB + b] = 1 | (1 << 2) | (fo << 3);
    }
    // is_sep accumulation (kept_dup = kept[pair] * lengths_mask), idx clamped
    if (kept && fe < len) atomicAdd(&sep_lds[min(excl_e, NEWF - 1)], 1);
    if (kept && fo < len) atomicAdd(&sep_lds[min(excl_o, NEWF - 1)], 1);
  }
  __syncthreads();

  for (int s = t; s < NEWF; s += 256) sep[s * BB + b] = sep_lds[s];

  // seq_losses reduce
  sdbl[t] = seq;
  __syncthreads();
  for (int off = 128; off; off >>= 1) {
    if (t < off) sdbl[t] += sdbl[t + off];
    __syncthreads();
  }
  if (t == 0) {
    out_tail[b]      = (float)(total < NEWF ? total : NEWF);  // new_lengths
    out_tail[BB + b] = (float)sdbl[0];                        // seq_losses
  }
}

// ---------------------------------------------------------------------------
// Kernel D: gather. One block per (slot, b); 128 threads x float4 = 512 floats.
// y[s,b,c] = scale*x[f,b,c] (+0.5*x[f-1,b,c] if two) + sep_cnt*is_sep[c]
// ---------------------------------------------------------------------------
__global__ __launch_bounds__(128) void gather_kernel(
    const float* __restrict__ x, const int* __restrict__ rec,
    const int* __restrict__ sep, const float* __restrict__ is_sep,
    float* __restrict__ y) {
  int s = blockIdx.x;
  int b = blockIdx.y;
  int r = rec[s * BB + b];
  int cv = sep[s * BB + b];
  int c = threadIdx.x * 4;

  float4 acc = make_float4(0.f, 0.f, 0.f, 0.f);
  if (r & 1) {
    int f = r >> 3;
    float sc = (r & 4) ? 0.5f : 1.0f;
    float4 xv = *(const float4*)(x + ((size_t)f * BB + b) * CC + c);
    acc.x = sc * xv.x; acc.y = sc * xv.y; acc.z = sc * xv.z; acc.w = sc * xv.w;
    if (r & 2) {
      float4 x2 = *(const float4*)(x + ((size_t)(f - 1) * BB + b) * CC + c);
      acc.x += 0.5f * x2.x; acc.y += 0.5f * x2.y;
      acc.z += 0.5f * x2.z; acc.w += 0.5f * x2.w;
    }
  }
  if (cv) {
    float fc = (float)cv;
    float4 is = *(const float4*)(is_sep + c);
    acc.x += fc * is.x; acc.y += fc * is.y; acc.z += fc * is.z; acc.w += fc * is.w;
  }
  *(float4*)(y + ((size_t)s * BB + b) * CC + c) = acc;
}

// ---------------------------------------------------------------------------
extern "C" void kernel_launch(void* const* d_in, const int* in_sizes, int n_in,
                              void* d_out, int out_size, void* d_ws, size_t ws_size,
                              hipStream_t stream) {
  (void)in_sizes; (void)n_in; (void)out_size; (void)ws_size;
  const float* x       = (const float*)d_in[0];
  const int*   lengths = (const int*)d_in[1];
  const float* rand_u  = (const float*)d_in[2];
  const float* W       = (const float*)d_in[3];
  const float* bias    = (const float*)d_in[4];
  const float* is_sep  = (const float*)d_in[5];

  float* y = (float*)d_out;
  float* out_tail = y + (size_t)NEWF * BB * CC;   // [new_lengths(32), seq_losses(32)]

  char* ws = (char*)d_ws;
  double* pred = (double*)ws;                                  // 1 MB
  int* rec = (int*)(ws + (size_t)BB * NPAIR * 2 * sizeof(double));
  int* sep = rec + (size_t)NEWF * BB;

  pred_kernel<<<(NPAIR * BB) / 4, 256, 0, stream>>>(x, W, bias, pred);
  scan_kernel<<<BB, 256, 0, stream>>>(pred, rand_u, lengths, rec, sep, out_tail);
  gather_kernel<<<dim3(NEWF, BB), 128, 0, stream>>>(x, rec, sep, is_sep, y);
}

// Round 3
// 96.208 us; speedup vs baseline: 1.1193x; 1.1193x over previous
//
#include <hip/hip_runtime.h>
#include <math.h>

#define FF 4096
#define NPAIR 2048
#define BB 32
#define CC 512
#define NEWF 3073   // int(1 + 4096*0.75)

typedef float f32x4 __attribute__((ext_vector_type(4)));

// ---------------------------------------------------------------------------
// Kernel A: pred[b][f2][{0,1}] = dot(x[2*f2,b,:], W[o,:]) + bias[o]  (fp64)
// One wave per (f2,b) row; 4 waves/block.
// ---------------------------------------------------------------------------
__global__ __launch_bounds__(256) void pred_kernel(
    const float* __restrict__ x, const float* __restrict__ W,
    const float* __restrict__ bias, double* __restrict__ pred) {
  int wave = threadIdx.x >> 6;
  int lane = threadIdx.x & 63;
  int row  = blockIdx.x * 4 + wave;        // row in [0, NPAIR*BB)
  int f2 = row >> 5;                        // / BB
  int b  = row & 31;
  const float* xr = x + ((size_t)(2 * f2) * BB + b) * CC;

  double s0 = 0.0, s1 = 0.0;
#pragma unroll
  for (int k = 0; k < 2; ++k) {
    int c = lane * 4 + k * 256;
    f32x4 xv = __builtin_nontemporal_load((const f32x4*)(xr + c));
    f32x4 w0 = *(const f32x4*)(W + c);
    f32x4 w1 = *(const f32x4*)(W + CC + c);
    s0 += (double)xv.x * (double)w0.x + (double)xv.y * (double)w0.y +
          (double)xv.z * (double)w0.z + (double)xv.w * (double)w0.w;
    s1 += (double)xv.x * (double)w1.x + (double)xv.y * (double)w1.y +
          (double)xv.z * (double)w1.z + (double)xv.w * (double)w1.w;
  }
#pragma unroll
  for (int off = 32; off; off >>= 1) {
    s0 += __shfl_down(s0, off, 64);
    s1 += __shfl_down(s1, off, 64);
  }
  if (lane == 0) {
    size_t o = ((size_t)b * NPAIR + f2) * 2;
    pred[o + 0] = s0 + (double)bias[0];
    pred[o + 1] = s1 + (double)bias[1];
  }
}

// ---------------------------------------------------------------------------
// Kernel C: per-b std, keep decisions, cumsum scan, per-slot contributor
// records, new_lengths, seq_losses, tail sep count. One block (1024 thr) per b.
// rec bits: 0 valid | 1 two-contrib | 2 scale-half | 3 sep | frame<<4
// ---------------------------------------------------------------------------
__global__ __launch_bounds__(1024) void scan_kernel(
    const double* __restrict__ pred, const float* __restrict__ rand_u,
    const int* __restrict__ lengths, int* __restrict__ rec,
    int* __restrict__ tail, float* __restrict__ out_tail) {
  int b = blockIdx.x;
  int t = threadIdx.x;
  int lane = t & 63, wid = t >> 6;          // 16 waves

  __shared__ double wdbl[16];
  __shared__ int    wint[16];
  __shared__ double s_invs;

  int len = lengths[b];
  const double* pb = pred + (size_t)b * NPAIR * 2;

  // two pairs per thread: pr0 = 2t, pr1 = 2t+1
  double2 a0 = ((const double2*)pb)[2 * t];
  double2 a1 = ((const double2*)pb)[2 * t + 1];
  double d0 = a0.x - a0.y;
  double d1 = a1.x - a1.y;

  // ---- std over frame axis (fp64) ----
  double sumsq = 0.25 * (d0 * d0 + d1 * d1);
#pragma unroll
  for (int off = 32; off; off >>= 1) sumsq += __shfl_down(sumsq, off, 64);
  if (lane == 0) wdbl[wid] = sumsq;
  __syncthreads();
  if (t == 0) {
    double s = 0;
#pragma unroll
    for (int i = 0; i < 16; ++i) s += wdbl[i];
    s_invs = -3.0 / sqrt(s / (double)NPAIR + 1e-20);
  }
  __syncthreads();
  double si = s_invs;

  // ---- decisions ----
  int pr0 = 2 * t, pr1 = 2 * t + 1;
  double prob0 = 1.0 / (1.0 + exp(-d0 * si));
  double prob1 = 1.0 / (1.0 + exp(-d1 * si));
  bool kept0 = prob0 > (double)rand_u[(size_t)pr0 * BB + b];
  bool kept1 = prob1 > (double)rand_u[(size_t)pr1 * BB + b];
  bool oe0 = (2 * pr0 < len) && kept0;
  bool oo0 = (2 * pr0 + 1) < len;
  bool oe1 = (2 * pr1 < len) && kept1;
  bool oo1 = (2 * pr1 + 1) < len;
  int cnt = (int)oe0 + (int)oo0 + (int)oe1 + (int)oo1;

  // ---- inclusive scan of cnt: wave shfl scan + cross-wave combine ----
  int sc = cnt;
#pragma unroll
  for (int off = 1; off < 64; off <<= 1) {
    int v = __shfl_up(sc, off, 64);
    if (lane >= off) sc += v;
  }
  if (lane == 63) wint[wid] = sc;
  __syncthreads();
  int wprefix = 0, total = 0;
#pragma unroll
  for (int i = 0; i < 16; ++i) {
    int wv = wint[i];
    if (i < wid) wprefix += wv;
    total += wv;
  }
  int base = wprefix + sc - cnt;

  // ---- zero this b's rec row (coalesced) ----
  int* rrow = rec + (size_t)b * NEWF;
  for (int s = t; s < NEWF; s += 1024) rrow[s] = 0;
  __syncthreads();

  // ---- write slot records ----
  int excl = base;
  int tailc = 0;
  double seq = (kept0 ? a0.x : a0.y) + (kept1 ? a1.x : a1.y);

#pragma unroll
  for (int i = 0; i < 2; ++i) {
    int pr = 2 * t + i;
    bool kept = i ? kept1 : kept0;
    bool oe = i ? oe1 : oe0;
    bool oo = i ? oo1 : oo0;
    int fe = 2 * pr, fo = fe + 1;
    int excl_e = excl; excl += (int)oe;
    int excl_o = excl; excl += (int)oo;

    if (oe) {
      if (excl_e < NEWF) {
        int half = oo ? 0 : 1;               // pair_mean 1.0 or 0.5
        rrow[excl_e] = 1 | (half << 2) | (1 << 3) | (fe << 4);
      }
      if (excl_e >= NEWF - 1) tailc++;       // kept in-length even, clamped sep
    }
    if (oo) {
      if (excl_o < NEWF) {
        int two  = kept ? 0 : 1;
        int half = kept ? 0 : 1;
        rrow[excl_o] = 1 | (two << 1) | (half << 2) | ((kept ? 1 : 0) << 3) | (fo << 4);
      }
      if (kept && excl_o >= NEWF - 1) tailc++;  // kept in-length odd, clamped sep
    }
    // boundary: odd past length, even partner kept -> 0.5-scaled contributor
    if (!oo && oe && excl_o < NEWF) {
      rrow[excl_o] = 1 | (1 << 2) | (fo << 4);
    }
  }

  // ---- reduce seq_losses and tail count ----
#pragma unroll
  for (int off = 32; off; off >>= 1) {
    seq   += __shfl_down(seq, off, 64);
    tailc += __shfl_down(tailc, off, 64);
  }
  __syncthreads();          // wdbl/wint reuse
  if (lane == 0) { wdbl[wid] = seq; wint[wid] = tailc; }
  __syncthreads();
  if (t == 0) {
    double ss = 0; int tc = 0;
#pragma unroll
    for (int i = 0; i < 16; ++i) { ss += wdbl[i]; tc += wint[i]; }
    tail[b] = tc;
    out_tail[b]      = (float)(total < NEWF ? total : NEWF);  // new_lengths
    out_tail[BB + b] = (float)ss;                             // seq_losses
  }
}

// ---------------------------------------------------------------------------
// Kernel D: gather. One block per (slot, b); 128 threads x float4 = 512 floats.
// y[s,b,c] = scale*x[f,b,c] (+0.5*x[f-1,b,c] if two) + sep_cnt*is_sep[c]
// ---------------------------------------------------------------------------
__global__ __launch_bounds__(128) void gather_kernel(
    const float* __restrict__ x, const int* __restrict__ rec,
    const int* __restrict__ tail, const float* __restrict__ is_sep,
    float* __restrict__ y) {
  int s = blockIdx.x;
  int b = blockIdx.y;
  int r = rec[(size_t)b * NEWF + s];
  int c = threadIdx.x * 4;

  int cv = (s == NEWF - 1) ? tail[b] : ((r >> 3) & 1);

  f32x4 acc = (f32x4)(0.f);
  if (r & 1) {
    int f = r >> 4;
    float sc = (r & 4) ? 0.5f : 1.0f;
    f32x4 xv = __builtin_nontemporal_load((const f32x4*)(x + ((size_t)f * BB + b) * CC + c));
    acc = sc * xv;
    if (r & 2) {
      f32x4 x2 = __builtin_nontemporal_load((const f32x4*)(x + ((size_t)(f - 1) * BB + b) * CC + c));
      acc += 0.5f * x2;
    }
  }
  if (cv) {
    float fc = (float)cv;
    f32x4 is = *(const f32x4*)(is_sep + c);
    acc += fc * is;
  }
  __builtin_nontemporal_store(acc, (f32x4*)(y + ((size_t)s * BB + b) * CC + c));
}

// ---------------------------------------------------------------------------
extern "C" void kernel_launch(void* const* d_in, const int* in_sizes, int n_in,
                              void* d_out, int out_size, void* d_ws, size_t ws_size,
                              hipStream_t stream) {
  (void)in_sizes; (void)n_in; (void)out_size; (void)ws_size;
  const float* x       = (const float*)d_in[0];
  const int*   lengths = (const int*)d_in[1];
  const float* rand_u  = (const float*)d_in[2];
  const float* W       = (const float*)d_in[3];
  const float* bias    = (const float*)d_in[4];
  const float* is_sep  = (const float*)d_in[5];

  float* y = (float*)d_out;
  float* out_tail = y + (size_t)NEWF * BB * CC;   // [new_lengths(32), seq_losses(32)]

  char* ws = (char*)d_ws;
  double* pred = (double*)ws;                                  // 1 MB
  int* rec  = (int*)(ws + (size_t)BB * NPAIR * 2 * sizeof(double));
  int* tail = rec + (size_t)BB * NEWF;

  pred_kernel<<<(NPAIR * BB) / 4, 256, 0, stream>>>(x, W, bias, pred);
  scan_kernel<<<BB, 1024, 0, stream>>>(pred, rand_u, lengths, rec, tail, out_tail);
  gather_kernel<<<dim3(NEWF, BB), 128, 0, stream>>>(x, rec, tail, is_sep, y);
}